// Round 2
// baseline (359.420 us; speedup 1.0000x reference)
//
#include <hip/hip_runtime.h>
#include <hip/hip_bf16.h>

#define Bc 2
#define Nc 2048
#define Dc 2048
#define Hc 32
#define KVHc 8

typedef __attribute__((ext_vector_type(4))) float f32x4;
typedef __attribute__((ext_vector_type(8))) short short8;

__device__ __forceinline__ ushort f2b(float f) {
  union { float f; unsigned u; } v; v.f = f;
  unsigned u = v.u;
  unsigned r = (u + 0x7FFFu + ((u >> 16) & 1u)) >> 16;
  return (ushort)r;
}
__device__ __forceinline__ float b2f(ushort h) {
  union { unsigned u; float f; } v; v.u = ((unsigned)h) << 16; return v.f;
}

__device__ __forceinline__ void gload_lds16(const ushort* g, ushort* l) {
  __builtin_amdgcn_global_load_lds(
      (const __attribute__((address_space(1))) void*)g,
      (__attribute__((address_space(3))) void*)l, 16, 0, 0);
}

// Stage a [ROWS][64] bf16 row-major tile (arbitrary global row stride, elems)
// into LDS linearly, with INVERSE-swizzled global source so reads can use
// byte_off ^ ((row&7)<<4)  (rule #21: both-sides-or-neither).
template<int ITERS>
__device__ __forceinline__ void stage_tile(const ushort* gbase, int gstride,
                                           ushort* lds, int tid) {
  #pragma unroll
  for (int i = 0; i < ITERS; ++i) {
    int s = i * 256 + tid;
    int row = s >> 3;
    int sch = (s & 7) ^ (row & 7);
    gload_lds16(gbase + (size_t)row * gstride + sch * 8, lds + s * 8);
  }
}

// Read one 8-bf16 MFMA fragment (8 contiguous k) from a swizzled [*][64] tile.
__device__ __forceinline__ short8 read_frag(const ushort* lds, int row, int kbyte) {
  int off = kbyte ^ ((row & 7) << 4);
  return *(const short8*)((const char*)lds + row * 128 + off);
}

__global__ void k_convert(const float* __restrict__ src, ushort* __restrict__ dst, int n4) {
  int i = blockIdx.x * 256 + threadIdx.x;
  if (i >= n4) return;
  float4 v = ((const float4*)src)[i];
  ushort4 o;
  o.x = f2b(v.x); o.y = f2b(v.y); o.z = f2b(v.z); o.w = f2b(v.w);
  *(ushort4*)&dst[(size_t)i * 4] = o;
}

__global__ void k_rope_table(float* __restrict__ cosT, float* __restrict__ sinT) {
  int i = blockIdx.x * 256 + threadIdx.x;  // N*32 = 65536
  int n = i >> 5, f = i & 31;
  float inv = powf(10000.0f, -(float)f * (1.0f / 32.0f));
  float ang = (float)n * inv;
  cosT[i] = cosf(ang);
  sinT[i] = sinf(ang);
}

// C[M,N] = A[M,K] @ B[N,K]^T, bf16 in, f32 accum, TOUT out (bf16 or f32).
// 128x128 tile, BK=64, 4 waves (2x2), each wave 64x64 = 4x4 frags 16x16x32.
template<typename TOUT>
__global__ __launch_bounds__(256) void k_gemm_bt(
    const ushort* __restrict__ A, const ushort* __restrict__ Bm,
    TOUT* __restrict__ C, int M, int Nn, int K) {
  __shared__ ushort ldsA[128 * 64];
  __shared__ ushort ldsB[128 * 64];
  int nt = Nn >> 7;
  int m0 = (int)(blockIdx.x / nt) << 7;
  int n0 = (int)(blockIdx.x % nt) << 7;
  int tid = threadIdx.x;
  int lane = tid & 63, w = tid >> 6;
  int wr = w >> 1, wc = w & 1;
  int lc = lane & 15, lq = lane >> 4;
  f32x4 acc[4][4];
  #pragma unroll
  for (int r = 0; r < 4; ++r)
    #pragma unroll
    for (int c = 0; c < 4; ++c) acc[r][c] = (f32x4){0.f, 0.f, 0.f, 0.f};
  int nkt = K >> 6;
  for (int kt = 0; kt < nkt; ++kt) {
    stage_tile<4>(A + (size_t)m0 * K + kt * 64, K, ldsA, tid);
    stage_tile<4>(Bm + (size_t)n0 * K + kt * 64, K, ldsB, tid);
    __syncthreads();  // drains vmcnt(0) for global_load_lds per guide
    #pragma unroll
    for (int kk = 0; kk < 2; ++kk) {
      int kbyte = kk * 64 + lq * 16;
      short8 af[4], bfr[4];
      #pragma unroll
      for (int r = 0; r < 4; ++r) af[r] = read_frag(ldsA, wr * 64 + r * 16 + lc, kbyte);
      #pragma unroll
      for (int c = 0; c < 4; ++c) bfr[c] = read_frag(ldsB, wc * 64 + c * 16 + lc, kbyte);
      #pragma unroll
      for (int r = 0; r < 4; ++r)
        #pragma unroll
        for (int c = 0; c < 4; ++c)
          acc[r][c] = __builtin_amdgcn_mfma_f32_16x16x32_bf16(af[r], bfr[c], acc[r][c], 0, 0, 0);
    }
    __syncthreads();
  }
  #pragma unroll
  for (int r = 0; r < 4; ++r)
    #pragma unroll
    for (int c = 0; c < 4; ++c) {
      int gr = m0 + wr * 64 + r * 16 + lq * 4;
      int gc = n0 + wc * 64 + c * 16 + lc;
      #pragma unroll
      for (int e = 0; e < 4; ++e) {
        float val = acc[r][c][e];
        if constexpr (sizeof(TOUT) == 2)
          C[(size_t)(gr + e) * Nn + gc] = f2b(val);
        else
          C[(size_t)(gr + e) * Nn + gc] = val;
      }
    }
}

// RoPE on Q (with 1/sqrt(hd)=0.125 folded in, exact in bf16) and K; also
// reshapes to [B,H,N,64] / [B,KVH,N,64].
__global__ void k_rope_qk(const ushort* __restrict__ qkv,
                          const float* __restrict__ cosT, const float* __restrict__ sinT,
                          ushort* __restrict__ qr, ushort* __restrict__ kr) {
  int bn = blockIdx.x;  // b*N + n
  int b = bn >> 11, n = bn & (Nc - 1);
  int t = threadIdx.x;
  const ushort* row = qkv + (size_t)bn * 3072;
  #pragma unroll
  for (int i = 0; i < 4; ++i) {
    int p = i * 256 + t;          // 1024 (h,dp) pairs
    int h = p >> 5, dp = p & 31;
    float c = cosT[n * 32 + dp], s = sinT[n * 32 + dp];
    float q0 = b2f(row[h * 64 + dp]);
    float q1 = b2f(row[h * 64 + dp + 32]);
    size_t ob = ((size_t)(b * Hc + h) * Nc + n) * 64 + dp;
    qr[ob]      = f2b((q0 * c - q1 * s) * 0.125f);
    qr[ob + 32] = f2b((q1 * c + q0 * s) * 0.125f);
  }
  {
    int kvh = t >> 5, dp = t & 31;  // 256 (kvh,dp) pairs
    float c = cosT[n * 32 + dp], s = sinT[n * 32 + dp];
    float k0 = b2f(row[2048 + kvh * 64 + dp]);
    float k1 = b2f(row[2048 + kvh * 64 + dp + 32]);
    size_t ob = ((size_t)(b * KVHc + kvh) * Nc + n) * 64 + dp;
    kr[ob]      = f2b(k0 * c - k1 * s);
    kr[ob + 32] = f2b(k1 * c + k0 * s);
  }
}

// V[B,N,kvh*64+d] (cols 2560.. of qkv) -> Vt[B,KVH,64,N] via LDS transpose.
__global__ void k_transpose_v(const ushort* __restrict__ qkv, ushort* __restrict__ vt) {
  __shared__ ushort tile[64][72];
  int bid = blockIdx.x;             // b*256.. : (b, kvh, ntile)
  int ntile = bid & 31, kvh = (bid >> 5) & 7, b = bid >> 8;
  int t = threadIdx.x;
  int n0 = ntile * 64;
  #pragma unroll
  for (int i = 0; i < 4; ++i) {
    int s = i * 256 + t;
    int r = s >> 4, c4 = s & 15;
    ushort4 v = *(const ushort4*)&qkv[(size_t)(b * Nc + n0 + r) * 3072 + 2560 + kvh * 64 + c4 * 4];
    tile[r][c4 * 4 + 0] = v.x; tile[r][c4 * 4 + 1] = v.y;
    tile[r][c4 * 4 + 2] = v.z; tile[r][c4 * 4 + 3] = v.w;
  }
  __syncthreads();
  #pragma unroll
  for (int i = 0; i < 4; ++i) {
    int s = i * 256 + t;
    int d = s >> 4, c4 = s & 15;
    ushort4 v;
    v.x = tile[c4 * 4 + 0][d]; v.y = tile[c4 * 4 + 1][d];
    v.z = tile[c4 * 4 + 2][d]; v.w = tile[c4 * 4 + 3][d];
    *(ushort4*)&vt[(size_t)((b * KVHc + kvh) * 64 + d) * Nc + n0 + c4 * 4] = v;
  }
}

// Flash attention. Block = (b, h, 64 q-rows); 4 waves x 16 q-rows each.
// K/V tiles (64 kv) staged to LDS (shared across waves), online softmax,
// P via padded LDS round-trip. Output ctx[b,n,h*64+d] bf16.
__global__ __launch_bounds__(256) void k_attn(
    const ushort* __restrict__ qr, const ushort* __restrict__ kr,
    const ushort* __restrict__ vt, ushort* __restrict__ ctx) {
  __shared__ ushort ldsK[64 * 64];
  __shared__ ushort ldsV[64 * 64];
  __shared__ ushort P[4][16][72];
  int bid = blockIdx.x;
  int qt = bid & 31, h = (bid >> 5) & 31, b = bid >> 10;
  int kvh = h >> 2;
  int tid = threadIdx.x;
  int w = tid >> 6, lane = tid & 63;
  int lc = lane & 15, lq = lane >> 4;
  int q0 = qt * 64 + w * 16;
  const ushort* Qb = qr + (size_t)(b * Hc + h) * Nc * 64;
  const ushort* Kb = kr + (size_t)(b * KVHc + kvh) * Nc * 64;
  const ushort* Vb = vt + (size_t)(b * KVHc + kvh) * 64 * Nc;
  short8 aq[2];
  #pragma unroll
  for (int kk = 0; kk < 2; ++kk)
    aq[kk] = *(const short8*)&Qb[(size_t)(q0 + lc) * 64 + kk * 32 + lq * 8];
  f32x4 oacc[4];
  #pragma unroll
  for (int d = 0; d < 4; ++d) oacc[d] = (f32x4){0.f, 0.f, 0.f, 0.f};
  float mrun[4], lrun[4];
  #pragma unroll
  for (int r = 0; r < 4; ++r) { mrun[r] = -1e30f; lrun[r] = 0.f; }

  for (int kvt = 0; kvt < Nc / 64; ++kvt) {
    int kbase = kvt * 64;
    stage_tile<2>(Kb + (size_t)kbase * 64, 64, ldsK, tid);
    stage_tile<2>(Vb + kbase, Nc, ldsV, tid);
    __syncthreads();
    // S = (Q*0.125) @ K^T for this wave's 16 q-rows x 64 kv
    f32x4 sc[4];
    #pragma unroll
    for (int c = 0; c < 4; ++c) {
      f32x4 a = (f32x4){0.f, 0.f, 0.f, 0.f};
      #pragma unroll
      for (int kk = 0; kk < 2; ++kk)
        a = __builtin_amdgcn_mfma_f32_16x16x32_bf16(
            aq[kk], read_frag(ldsK, c * 16 + lc, kk * 64 + lq * 16), a, 0, 0, 0);
      sc[c] = a;
    }
    // online softmax (rows live on 16-lane groups; reduce width 16)
    float al[4], rs[4];
    #pragma unroll
    for (int r = 0; r < 4; ++r) {
      float m = fmaxf(fmaxf(sc[0][r], sc[1][r]), fmaxf(sc[2][r], sc[3][r]));
      #pragma unroll
      for (int off = 1; off < 16; off <<= 1) m = fmaxf(m, __shfl_xor(m, off, 16));
      float mn = fmaxf(mrun[r], m);
      al[r] = __expf(mrun[r] - mn);
      mrun[r] = mn;
      rs[r] = 0.f;
    }
    #pragma unroll
    for (int c = 0; c < 4; ++c)
      #pragma unroll
      for (int r = 0; r < 4; ++r) {
        float p = __expf(sc[c][r] - mrun[r]);
        sc[c][r] = p;
        rs[r] += p;
      }
    #pragma unroll
    for (int r = 0; r < 4; ++r) {
      #pragma unroll
      for (int off = 1; off < 16; off <<= 1) rs[r] += __shfl_xor(rs[r], off, 16);
      lrun[r] = lrun[r] * al[r] + rs[r];
    }
    #pragma unroll
    for (int dd = 0; dd < 4; ++dd)
      #pragma unroll
      for (int r = 0; r < 4; ++r) oacc[dd][r] *= al[r];
    // P (bf16) to per-wave LDS region, D-layout -> A-layout transpose
    #pragma unroll
    for (int c = 0; c < 4; ++c)
      #pragma unroll
      for (int r = 0; r < 4; ++r)
        P[w][lq * 4 + r][c * 16 + lc] = f2b(sc[c][r]);
    __syncthreads();
    // O += P @ V
    #pragma unroll
    for (int kk = 0; kk < 2; ++kk) {
      short8 pa = *(const short8*)&P[w][lc][kk * 32 + lq * 8];
      #pragma unroll
      for (int dd = 0; dd < 4; ++dd)
        oacc[dd] = __builtin_amdgcn_mfma_f32_16x16x32_bf16(
            pa, read_frag(ldsV, dd * 16 + lc, kk * 64 + lq * 16), oacc[dd], 0, 0, 0);
    }
    __syncthreads();  // protect ldsK/ldsV from next iteration's staging
  }
  #pragma unroll
  for (int dd = 0; dd < 4; ++dd)
    #pragma unroll
    for (int r = 0; r < 4; ++r) {
      float v = oacc[dd][r] / lrun[r];
      ctx[(size_t)(b * Nc + q0 + lq * 4 + r) * Dc + h * 64 + dd * 16 + lc] = f2b(v);
    }
}

extern "C" void kernel_launch(void* const* d_in, const int* in_sizes, int n_in,
                              void* d_out, int out_size, void* d_ws, size_t ws_size,
                              hipStream_t stream) {
  const float* x  = (const float*)d_in[0];
  const float* Wq = (const float*)d_in[1];
  const float* Wk = (const float*)d_in[2];
  const float* Wv = (const float*)d_in[3];
  const float* Wo = (const float*)d_in[4];

  ushort* ws   = (ushort*)d_ws;
  ushort* xb   = ws;                       // 8,388,608  bf16  (x)
  ushort* wqkv = xb + 8388608;             // 6,291,456  bf16  (Wq|Wk|Wv rows)
  ushort* wob  = wqkv + 6291456;           // 4,194,304  bf16
  float*  cosT = (float*)(wob + 4194304);  // 65,536 f32
  float*  sinT = cosT + 65536;             // 65,536 f32
  ushort* qkv  = (ushort*)(sinT + 65536);  // 12,582,912 bf16
  ushort* qr   = qkv + 12582912;           // 8,388,608
  ushort* kr   = qr + 8388608;             // 2,097,152
  ushort* vt   = kr + 2097152;             // 2,097,152
  ushort* ctx  = vt + 2097152;             // 8,388,608   (~100.5 MB total)

  k_convert<<<8192, 256, 0, stream>>>(x, xb, 2097152);
  k_convert<<<4096, 256, 0, stream>>>(Wq, wqkv, 1048576);
  k_convert<<<1024, 256, 0, stream>>>(Wk, wqkv + 4194304, 262144);
  k_convert<<<1024, 256, 0, stream>>>(Wv, wqkv + 5242880, 262144);
  k_convert<<<4096, 256, 0, stream>>>(Wo, wob, 1048576);
  k_rope_table<<<256, 256, 0, stream>>>(cosT, sinT);

  // QKV = x @ [Wq;Wk;Wv]^T : [4096,2048] x [3072,2048]^T
  k_gemm_bt<ushort><<<768, 256, 0, stream>>>(xb, wqkv, qkv, 4096, 3072, 2048);
  k_rope_qk<<<4096, 256, 0, stream>>>(qkv, cosT, sinT, qr, kr);
  k_transpose_v<<<512, 256, 0, stream>>>(qkv, vt);
  k_attn<<<2048, 256, 0, stream>>>(qr, kr, vt, ctx);
  // out = ctx @ Wo^T  (f32 output per reference dtype)
  k_gemm_bt<float><<<512, 256, 0, stream>>>(ctx, wob, (float*)d_out, 4096, 2048, 2048);
}